// Round 4
// baseline (352.359 us; speedup 1.0000x reference)
//
#include <hip/hip_runtime.h>

// SwinAttention1D fused: B=8, C=256, N=16384, W=16, H=4, hd=64.
// R4 (= R3 resubmit; R3 failed in infra before the kernel ran):
// 64-token blocks (4 windows), 1024 threads (16 waves), 1 block/CU.
// Halves per-CU weight streaming (the L1-path bottleneck): each weight
// fragment is reused across 4 token-subtiles. Wave wv owns q-tile wv,
// k-tile 16+wv, v-tile 32+wv in P2; pair (g=wv>>2, h=wv&3) in P3;
// out-tile wv in P4. Swapped-MFMA packed-b64 store layouts from R2 kept.

#define C_DIM 256
#define NSEQ  16384

typedef __attribute__((ext_vector_type(8))) short bf16x8;
typedef __attribute__((ext_vector_type(4))) float f32x4;

__device__ __forceinline__ unsigned short f2bf(float f) {
    unsigned int u = __builtin_bit_cast(unsigned int, f);
    u += 0x7FFFu + ((u >> 16) & 1u);   // RNE
    return (unsigned short)(u >> 16);
}
__device__ __forceinline__ float bf2f(unsigned short h) {
    unsigned int u = ((unsigned int)h) << 16;
    return __builtin_bit_cast(float, u);
}
__device__ __forceinline__ unsigned int pack2(float a, float b) {
    return ((unsigned int)f2bf(b) << 16) | (unsigned int)f2bf(a);
}
__device__ __forceinline__ uint2 pack4(f32x4 v) {
    uint2 r; r.x = pack2(v[0], v[1]); r.y = pack2(v[2], v[3]); return r;
}
// Row-stripe XOR swizzle (bit 4 of the column). All vector accesses stay
// inside one 16-col granule, so this is a consistent permutation.
__device__ __forceinline__ int xsw(int row, int col) {
    return col ^ (((row >> 3) & 1) << 4);
}

// Repack weights: dst[nt][k][l15][quad*8+j] = src[nt*16+l15][k*32+quad*8+j]
__global__ void prep_weights(const float* __restrict__ wq_f, const float* __restrict__ wo_f,
                             unsigned short* __restrict__ wq, unsigned short* __restrict__ wo) {
    int i = blockIdx.x * 256 + threadIdx.x;
    if (i < 768 * 256) {
        int nt = i >> 12, r = i & 4095;
        int k = r >> 9, r2 = r & 511;
        int l = r2 >> 5, r3 = r2 & 31;
        wq[i] = f2bf(wq_f[(nt * 16 + l) * 256 + k * 32 + r3]);
    }
    if (i < 256 * 256) {
        int nt = i >> 12, r = i & 4095;
        int k = r >> 9, r2 = r & 511;
        int l = r2 >> 5, r3 = r2 & 31;
        wo[i] = f2bf(wo_f[(nt * 16 + l) * 256 + k * 32 + r3]);
    }
}

__global__ __launch_bounds__(1024, 4) void swin_fused(
    const float* __restrict__ x,
    const unsigned short* __restrict__ wq,   // bf16, repacked [48][8][16][32]
    const unsigned short* __restrict__ wo,   // bf16, repacked [16][8][16][32]
    const float* __restrict__ bq,
    const float* __restrict__ bo,
    const float* __restrict__ lng,
    const float* __restrict__ lnb,
    float* __restrict__ out)
{
    __shared__ __align__(16) unsigned short lds_x[64][264];   // token-major x, swizzled
    __shared__ __align__(16) unsigned short lds_qk[64][520];  // q | k, swizzled; attn overlays q
    __shared__ __align__(16) unsigned short lds_vt[256][72];  // v^T [ch][tok]; reused as y later
    __shared__ __align__(16) unsigned short lds_p[16][16][16];
    __shared__ float lds_mean[64];
    __shared__ float lds_rstd[64];
    // 33792 + 66560 + 36864 + 8192 + 512 = 145920 B -> 1 block/CU (16 waves)

    const int tid  = threadIdx.x;
    const int wv   = tid >> 6;        // 0..15
    const int lane = tid & 63;
    const int l15  = lane & 15;
    const int quad = lane >> 4;

    const int w0    = blockIdx.x * 4;          // 4 windows per block
    const int batch = w0 >> 10;
    const int nbase = (w0 & 1023) << 4;
    const long xbase = (long)batch * ((long)C_DIM * NSEQ) + nbase;

    // ---------- Phase 1: x tile (64 tok x 256 ch) -> LDS bf16 ----------
    {
        const int t4 = (tid & 15) << 2;        // 4 tokens
        const int c4 = (tid >> 4) << 2;        // 4 channels
        float4 r[4];
        #pragma unroll
        for (int j = 0; j < 4; ++j)
            r[j] = *reinterpret_cast<const float4*>(&x[xbase + (long)(c4 + j) * NSEQ + t4]);
        const float* rf = reinterpret_cast<const float*>(r);
        #pragma unroll
        for (int i = 0; i < 4; ++i) {
            uint2 v;
            v.x = pack2(rf[0 * 4 + i], rf[1 * 4 + i]);
            v.y = pack2(rf[2 * 4 + i], rf[3 * 4 + i]);
            *reinterpret_cast<uint2*>(&lds_x[t4 + i][xsw(t4 + i, c4)]) = v;
        }
    }

    // prefetch Q weights (nt = wv) across the barrier
    const unsigned short* wqbase = wq + l15 * 32 + quad * 8;
    bf16x8 wA[8], wB[8];
    #pragma unroll
    for (int k = 0; k < 8; ++k)
        wA[k] = *reinterpret_cast<const bf16x8*>(wqbase + wv * 4096 + k * 512);

    __syncthreads();

    // ---------- Phase 2: QKV. Each wave: q-tile wv, k-tile 16+wv, v-tile 32+wv,
    //                     each weight fragment reused across 4 token-subtiles ----------
    // Q (swapped: C = W.x^T -> lane holds token=l15, 4 consecutive d)
    {
        #pragma unroll
        for (int k = 0; k < 8; ++k)            // prefetch K weights
            wB[k] = *reinterpret_cast<const bf16x8*>(wqbase + (16 + wv) * 4096 + k * 512);
        const float4 b4 = *reinterpret_cast<const float4*>(&bq[wv * 16 + quad * 4]);
        f32x4 acc[4];
        #pragma unroll
        for (int s = 0; s < 4; ++s) acc[s] = {b4.x, b4.y, b4.z, b4.w};
        #pragma unroll
        for (int k = 0; k < 8; ++k) {
            #pragma unroll
            for (int s = 0; s < 4; ++s) {
                const int row = s * 16 + l15;
                bf16x8 a = *reinterpret_cast<const bf16x8*>(&lds_x[row][xsw(row, k * 32 + quad * 8)]);
                acc[s] = __builtin_amdgcn_mfma_f32_16x16x32_bf16(wA[k], a, acc[s], 0, 0, 0);
            }
        }
        const int cb = wv * 16 + quad * 4;
        #pragma unroll
        for (int s = 0; s < 4; ++s) {
            const int row = s * 16 + l15;
            *reinterpret_cast<uint2*>(&lds_qk[row][xsw(row, cb)]) = pack4(acc[s]);
        }
    }
    // K (swapped)
    {
        #pragma unroll
        for (int k = 0; k < 8; ++k)            // prefetch V weights
            wA[k] = *reinterpret_cast<const bf16x8*>(wqbase + (32 + wv) * 4096 + k * 512);
        const float4 b4 = *reinterpret_cast<const float4*>(&bq[256 + wv * 16 + quad * 4]);
        f32x4 acc[4];
        #pragma unroll
        for (int s = 0; s < 4; ++s) acc[s] = {b4.x, b4.y, b4.z, b4.w};
        #pragma unroll
        for (int k = 0; k < 8; ++k) {
            #pragma unroll
            for (int s = 0; s < 4; ++s) {
                const int row = s * 16 + l15;
                bf16x8 a = *reinterpret_cast<const bf16x8*>(&lds_x[row][xsw(row, k * 32 + quad * 8)]);
                acc[s] = __builtin_amdgcn_mfma_f32_16x16x32_bf16(wB[k], a, acc[s], 0, 0, 0);
            }
        }
        const int cb = 256 + wv * 16 + quad * 4;
        #pragma unroll
        for (int s = 0; s < 4; ++s) {
            const int row = s * 16 + l15;
            *reinterpret_cast<uint2*>(&lds_qk[row][xsw(row, cb)]) = pack4(acc[s]);
        }
    }
    // V (normal: C = x.W^T -> lane holds d=l15, 4 consecutive tokens) into v^T
    {
        const float bias = bq[512 + wv * 16 + l15];
        f32x4 acc[4];
        #pragma unroll
        for (int s = 0; s < 4; ++s) acc[s] = {bias, bias, bias, bias};
        #pragma unroll
        for (int k = 0; k < 8; ++k) {
            #pragma unroll
            for (int s = 0; s < 4; ++s) {
                const int row = s * 16 + l15;
                bf16x8 a = *reinterpret_cast<const bf16x8*>(&lds_x[row][xsw(row, k * 32 + quad * 8)]);
                acc[s] = __builtin_amdgcn_mfma_f32_16x16x32_bf16(a, wA[k], acc[s], 0, 0, 0);
            }
        }
        #pragma unroll
        for (int s = 0; s < 4; ++s)
            *reinterpret_cast<uint2*>(&lds_vt[wv * 16 + l15][s * 16 + quad * 4]) = pack4(acc[s]);
    }
    __syncthreads();

    // ---------- Phase 3: attention, one (window, head) per wave ----------
    {
        const int g = wv >> 2;                 // 0..3
        const int h = wv & 3;                  // 0..3
        const int row = g * 16 + l15;
        f32x4 sc = {0.f, 0.f, 0.f, 0.f};
        #pragma unroll
        for (int kk = 0; kk < 2; ++kk) {
            bf16x8 aq = *reinterpret_cast<const bf16x8*>(&lds_qk[row][xsw(row, h * 64 + kk * 32 + quad * 8)]);
            bf16x8 bk = *reinterpret_cast<const bf16x8*>(&lds_qk[row][xsw(row, 256 + h * 64 + kk * 32 + quad * 8)]);
            sc = __builtin_amdgcn_mfma_f32_16x16x32_bf16(aq, bk, sc, 0, 0, 0);
        }
        #pragma unroll
        for (int r = 0; r < 4; ++r) {
            float s = sc[r] * 0.125f;          // 1/sqrt(hd)
            float m = s;
            #pragma unroll
            for (int msk = 1; msk <= 8; msk <<= 1) m = fmaxf(m, __shfl_xor(m, msk, 16));
            float e = __expf(s - m);
            float su = e;
            #pragma unroll
            for (int msk = 1; msk <= 8; msk <<= 1) su += __shfl_xor(su, msk, 16);
            lds_p[wv][quad * 4 + r][l15] = f2bf(e / su);
        }
        // P @ v, swapped: C = V^T.P^T -> lane holds (token=l15, 4 consecutive d)
        bf16x8 ap = {0,0,0,0,0,0,0,0};
        if (quad < 2) ap = *reinterpret_cast<const bf16x8*>(&lds_p[wv][l15][quad * 8]);
        #pragma unroll
        for (int dt = 0; dt < 4; ++dt) {
            bf16x8 bv = {0,0,0,0,0,0,0,0};
            if (quad < 2)
                bv = *reinterpret_cast<const bf16x8*>(&lds_vt[h * 64 + dt * 16 + l15][g * 16 + quad * 8]);
            f32x4 acc = {0.f, 0.f, 0.f, 0.f};
            acc = __builtin_amdgcn_mfma_f32_16x16x32_bf16(bv, ap, acc, 0, 0, 0);
            const int cb = h * 64 + dt * 16 + quad * 4;
            *reinterpret_cast<uint2*>(&lds_qk[row][xsw(row, cb)]) = pack4(acc);
        }
    }

    // prefetch P4 weights (out-tile wv) across the barrier
    const unsigned short* wobase = wo + l15 * 32 + quad * 8;
    #pragma unroll
    for (int k = 0; k < 8; ++k)
        wA[k] = *reinterpret_cast<const bf16x8*>(wobase + wv * 4096 + k * 512);

    __syncthreads();

    // ---------- Phase 4: out = attn @ Wo^T + b_o (swapped); y = out + x ----------
    unsigned short* ldy = &lds_vt[0][0];       // 64 x 264 = 16896 <= 18432 shorts
    {
        const float4 b4 = *reinterpret_cast<const float4*>(&bo[wv * 16 + quad * 4]);
        f32x4 acc[4];
        #pragma unroll
        for (int s = 0; s < 4; ++s) acc[s] = {b4.x, b4.y, b4.z, b4.w};
        #pragma unroll
        for (int k = 0; k < 8; ++k) {
            #pragma unroll
            for (int s = 0; s < 4; ++s) {
                const int row = s * 16 + l15;
                bf16x8 a = *reinterpret_cast<const bf16x8*>(&lds_qk[row][xsw(row, k * 32 + quad * 8)]);
                acc[s] = __builtin_amdgcn_mfma_f32_16x16x32_bf16(wA[k], a, acc[s], 0, 0, 0);
            }
        }
        const int cb = wv * 16 + quad * 4;
        #pragma unroll
        for (int s = 0; s < 4; ++s) {
            const int row = s * 16 + l15;
            uint2 xr = *reinterpret_cast<const uint2*>(&lds_x[row][xsw(row, cb)]);
            f32x4 y;
            y[0] = acc[s][0] + bf2f((unsigned short)(xr.x & 0xffff));
            y[1] = acc[s][1] + bf2f((unsigned short)(xr.x >> 16));
            y[2] = acc[s][2] + bf2f((unsigned short)(xr.y & 0xffff));
            y[3] = acc[s][3] + bf2f((unsigned short)(xr.y >> 16));
            *reinterpret_cast<uint2*>(&ldy[row * 264 + xsw(row, cb)]) = pack4(y);
        }
    }
    __syncthreads();

    // ---------- Phase 5a: LN stats (16 threads per token row, b128 reads) ----------
    {
        const int row = tid >> 4, part = tid & 15;    // 64 rows x 16 parts
        float s = 0.f, sq = 0.f;
        #pragma unroll
        for (int half = 0; half < 2; ++half) {
            bf16x8 yv = *reinterpret_cast<const bf16x8*>(&ldy[row * 264 + xsw(row, part * 16 + half * 8)]);
            #pragma unroll
            for (int ii = 0; ii < 8; ++ii) {
                float v = bf2f((unsigned short)yv[ii]);
                s += v; sq += v * v;
            }
        }
        #pragma unroll
        for (int msk = 1; msk <= 8; msk <<= 1) {
            s  += __shfl_xor(s,  msk, 16);
            sq += __shfl_xor(sq, msk, 16);
        }
        if (part == 0) {
            float mean = s * (1.0f / 256.0f);
            float var  = sq * (1.0f / 256.0f) - mean * mean;
            lds_mean[row] = mean;
            lds_rstd[row] = rsqrtf(var + 1e-5f);
        }
    }
    __syncthreads();

    // ---------- Phase 5b: normalize + vectorized transposed store ----------
    {
        const int t4 = (tid & 15) << 2;        // 4 tokens
        const int c0 = tid >> 4;               // 0..63
        float mean[4], rstd[4];
        #pragma unroll
        for (int i = 0; i < 4; ++i) { mean[i] = lds_mean[t4 + i]; rstd[i] = lds_rstd[t4 + i]; }
        #pragma unroll
        for (int it = 0; it < 4; ++it) {
            const int c = c0 + (it << 6);
            const float g = lng[c], b = lnb[c];
            float4 o;
            float* of = reinterpret_cast<float*>(&o);
            #pragma unroll
            for (int i = 0; i < 4; ++i)
                of[i] = (bf2f(ldy[(t4 + i) * 264 + xsw(t4 + i, c)]) - mean[i]) * rstd[i] * g + b;
            *reinterpret_cast<float4*>(&out[xbase + (long)c * NSEQ + t4]) = o;
        }
    }
}

extern "C" void kernel_launch(void* const* d_in, const int* in_sizes, int n_in,
                              void* d_out, int out_size, void* d_ws, size_t ws_size,
                              hipStream_t stream) {
    const float* x   = (const float*)d_in[0];
    const float* ipw = (const float*)d_in[1];
    const float* ipb = (const float*)d_in[2];
    const float* opw = (const float*)d_in[3];
    const float* opb = (const float*)d_in[4];
    const float* lng = (const float*)d_in[5];
    const float* lnb = (const float*)d_in[6];
    float* out = (float*)d_out;

    unsigned short* wq = (unsigned short*)d_ws;
    unsigned short* wo = wq + 768 * 256;

    prep_weights<<<768, 256, 0, stream>>>(ipw, opw, wq, wo);
    swin_fused<<<2048, 1024, 0, stream>>>(x, wq, wo, ipb, opb, lng, lnb, out);
}